// Round 1
// baseline (198.843 us; speedup 1.0000x reference)
//
#include <hip/hip_runtime.h>
#include <math.h>

// Problem constants (fixed by the reference)
#define NA 2048   // agents
#define TT 20     // timesteps
#define KK 32     // neighbors
#define CC 32     // in channels
#define OO 64     // out channels / hidden
#define GG 256    // 4*OO gates
#define APB 4     // agents per block in lstm kernel

__device__ __forceinline__ float fast_rcp(float x) {
#if __has_builtin(__builtin_amdgcn_rcpf)
    return __builtin_amdgcn_rcpf(x);
#else
    return 1.0f / x;
#endif
}
__device__ __forceinline__ float sigm(float x) {
    return fast_rcp(1.f + __expf(-x));
}
__device__ __forceinline__ float tanh_fast(float x) {
    // 1 - 2/(exp(2x)+1); saturates correctly at +-inf
    return 1.f - 2.f * fast_rcp(1.f + __expf(2.f * x));
}

// Kernel 1: P[t][n][o] = sum_c x[n][t][c] * conv_w[o][c]
// One wave per (n,t) row; lane = o. conv_w transposed into LDS for
// coalesced (bank-conflict-free) lane reads.
__global__ __launch_bounds__(256) void proj_kernel(
    const float* __restrict__ x, const float* __restrict__ conv_w,
    float* __restrict__ P)
{
    __shared__ float wT[CC * OO];  // wT[c*64 + o] = conv_w[o*32 + c]
    for (int e = threadIdx.x; e < OO * CC; e += 256) {
        int o = e >> 5, c = e & 31;
        wT[c * OO + o] = conv_w[e];
    }
    __syncthreads();
    const int lane = threadIdx.x & 63;
    const int r = blockIdx.x * 4 + (threadIdx.x >> 6);  // r = n*TT + t
    if (r >= NA * TT) return;
    const int n = r / TT;
    const int t = r - n * TT;
    const float* xr = x + (size_t)r * CC;  // x[n][t][:], 128B aligned
    float xv[CC];
    #pragma unroll
    for (int c = 0; c < CC; c += 4) {
        float4 v = *(const float4*)(xr + c);  // wave-broadcast load
        xv[c] = v.x; xv[c + 1] = v.y; xv[c + 2] = v.z; xv[c + 3] = v.w;
    }
    float acc = 0.f;
    #pragma unroll
    for (int c = 0; c < CC; ++c)
        acc = fmaf(xv[c], wT[c * OO + lane], acc);
    P[((size_t)t * NA + n) * OO + lane] = acc;
}

// Kernel 2: fused gather-max + LSTM. Each block owns APB agents for the
// full T=20 recurrence (per-agent independence: h@w_hh.T mixes channels
// only). Thread j holds gate-row weights w_ih[j][:], w_hh[j][:] in
// registers (128 VGPRs); feat/h broadcast from LDS.
__global__ __launch_bounds__(256, 2) void lstm_kernel(
    const float* __restrict__ P, const int* __restrict__ A,
    const float* __restrict__ conv_b,
    const float* __restrict__ w_ih, const float* __restrict__ w_hh,
    const float* __restrict__ b_ih, const float* __restrict__ b_hh,
    float* __restrict__ out)
{
    const int tid = threadIdx.x;        // gate index j in [0,256)
    const int a0 = blockIdx.x * APB;    // first agent of this block

    // Per-thread gate weights in registers.
    float wih[OO], whh[OO];
    #pragma unroll
    for (int o = 0; o < OO; o += 4) {
        float4 v = *(const float4*)(w_ih + (size_t)tid * OO + o);
        wih[o] = v.x; wih[o + 1] = v.y; wih[o + 2] = v.z; wih[o + 3] = v.w;
        float4 u = *(const float4*)(w_hh + (size_t)tid * OO + o);
        whh[o] = u.x; whh[o + 1] = u.y; whh[o + 2] = u.z; whh[o + 3] = u.w;
    }
    // Fold conv_b into the gate bias: sum_o conv_b[o]*w_ih[j][o]
    float bj = b_ih[tid] + b_hh[tid];
    #pragma unroll
    for (int o = 0; o < OO; ++o) bj = fmaf(conv_b[o], wih[o], bj);

    __shared__ __align__(16) float feat_sh[APB][OO];
    __shared__ __align__(16) float h_sh[APB][OO];
    __shared__ __align__(16) float gsh[APB][GG];
    __shared__ int A_sh[APB * KK];

    const int pa = tid >> 6;   // (agent, channel) pair owned by this thread
    const int po = tid & 63;
    float c_reg = 0.f;
    h_sh[pa][po] = 0.f;        // APB*OO == 256: one element per thread

    for (int t = 0; t < TT; ++t) {
        if (tid < APB * KK)
            A_sh[tid] = A[((size_t)t * NA + a0) * KK + tid];
        __syncthreads();  // sync1: A_sh ready; also fences prev h_sh write

        // Gather-max: wave = one agent, lane = channel -> coalesced 256B rows
        const float* Pt = P + (size_t)t * NA * OO;
        float m = -INFINITY;
        #pragma unroll
        for (int k = 0; k < KK; ++k) {
            int idx = A_sh[pa * KK + k];          // wave-broadcast LDS read
            m = fmaxf(m, Pt[(size_t)idx * OO + po]);
        }
        feat_sh[pa][po] = m - Pt[(size_t)(a0 + pa) * OO + po];
        __syncthreads();  // sync2: feat ready

        // Gates: g[a][j] = bj + sum_o feat[a][o]*wih[o] + h[a][o]*whh[o]
        float g[APB];
        #pragma unroll
        for (int a = 0; a < APB; ++a) {
            float acc = bj;
            #pragma unroll
            for (int o = 0; o < OO; ++o)
                acc = fmaf(feat_sh[a][o], wih[o],
                           fmaf(h_sh[a][o], whh[o], acc));
            g[a] = acc;
        }
        #pragma unroll
        for (int a = 0; a < APB; ++a) gsh[a][tid] = g[a];
        __syncthreads();  // sync3: gates ready; all h_sh reads done

        // Pointwise update: this thread owns (pa, po); c stays in register.
        float ig = sigm(gsh[pa][po]);
        float fg = sigm(gsh[pa][OO + po]);
        float gg = tanh_fast(gsh[pa][2 * OO + po]);
        float og = sigm(gsh[pa][3 * OO + po]);
        c_reg = fmaf(fg, c_reg, ig * gg);
        float h = og * tanh_fast(c_reg);
        h_sh[pa][po] = h;  // next iter's sync1/sync2 fence this before reads
        out[((size_t)(a0 + pa) * TT + t) * OO + po] = h;
        if (t == TT - 1) {
            out[(size_t)NA * TT * OO + (size_t)(a0 + pa) * OO + po] = h;
            out[(size_t)NA * TT * OO + (size_t)NA * OO
                + (size_t)(a0 + pa) * OO + po] = c_reg;
        }
    }
}

extern "C" void kernel_launch(void* const* d_in, const int* in_sizes, int n_in,
                              void* d_out, int out_size, void* d_ws, size_t ws_size,
                              hipStream_t stream) {
    const float* x      = (const float*)d_in[0];
    const int*   A      = (const int*)  d_in[1];
    const float* conv_w = (const float*)d_in[2];
    const float* conv_b = (const float*)d_in[3];
    const float* w_ih   = (const float*)d_in[4];
    const float* w_hh   = (const float*)d_in[5];
    const float* b_ih   = (const float*)d_in[6];
    const float* b_hh   = (const float*)d_in[7];
    float* out = (float*)d_out;
    float* P   = (float*)d_ws;  // T*N*O floats = 10.5 MB scratch

    hipLaunchKernelGGL(proj_kernel, dim3(NA * TT / 4), dim3(256), 0, stream,
                       x, conv_w, P);
    hipLaunchKernelGGL(lstm_kernel, dim3(NA / APB), dim3(256), 0, stream,
                       P, A, conv_b, w_ih, w_hh, b_ih, b_hh, out);
}

// Round 2
// 186.078 us; speedup vs baseline: 1.0686x; 1.0686x over previous
//
#include <hip/hip_runtime.h>
#include <hip/hip_bf16.h>
#include <math.h>

#define NA 2048   // agents (2^11)
#define TT 20     // timesteps
#define KK 32     // neighbors
#define CC 32     // in channels
#define OO 64     // out channels / hidden
#define GG 256    // 4*OO gates

__device__ __forceinline__ float fast_rcp(float x) {
    return __builtin_amdgcn_rcpf(x);
}
__device__ __forceinline__ float sigm(float x) {
    return fast_rcp(1.f + __expf(-x));
}
__device__ __forceinline__ float tanh_fast(float x) {
    return 1.f - 2.f * fast_rcp(1.f + __expf(2.f * x));
}

// P[t][n][o] = sum_c x[n][t][c] * conv_w[o][c].  Lane = o, weights in regs,
// x row is wave-broadcast. 4 rows per wave, no LDS.
__global__ __launch_bounds__(256) void proj_kernel(
    const float* __restrict__ x, const float* __restrict__ conv_w,
    float* __restrict__ P)
{
    const int lane = threadIdx.x & 63;
    const int wv = threadIdx.x >> 6;
    float w[CC];
    #pragma unroll
    for (int c = 0; c < CC; c += 4) {
        float4 v = *(const float4*)(conv_w + lane * CC + c);
        w[c] = v.x; w[c + 1] = v.y; w[c + 2] = v.z; w[c + 3] = v.w;
    }
    const int rbase = blockIdx.x * 16 + wv * 4;
    #pragma unroll
    for (int i = 0; i < 4; ++i) {
        int r = rbase + i;                    // r = n*TT + t (x row order)
        const float* xr = x + (size_t)r * CC;
        float acc = 0.f;
        #pragma unroll
        for (int c = 0; c < CC; c += 4) {
            float4 v = *(const float4*)(xr + c);  // broadcast load
            acc = fmaf(v.x, w[c], acc);
            acc = fmaf(v.y, w[c + 1], acc);
            acc = fmaf(v.z, w[c + 2], acc);
            acc = fmaf(v.w, w[c + 3], acc);
        }
        int n = r / TT;
        int t = r - n * TT;
        P[(((size_t)t << 11) + n) * OO + lane] = acc;
    }
}

// Per (t,n) row: feat = max_k P_t[A[t,n,k]] - P_t[n];
// gx[row][j'] = bias_total[j] + sum_o feat[o]*w_ih[j][o], stored bf16,
// j' = oo*4 + gate so the lstm kernel reads it coalesced in its layout.
// Block: 256 threads; chunk of 4 rows (one gathered per wave); thread owns
// its w_ih row in regs; feat broadcast from (double-buffered) LDS.
__global__ __launch_bounds__(256) void gatemm_kernel(
    const float* __restrict__ P, const int* __restrict__ A,
    const float* __restrict__ conv_b, const float* __restrict__ w_ih,
    const float* __restrict__ b_ih, const float* __restrict__ b_hh,
    __hip_bfloat16* __restrict__ gx)
{
    const int tid = threadIdx.x;
    const int lane = tid & 63;
    const int wv = tid >> 6;
    const int gate = tid & 3;
    const int oo = tid >> 2;
    const int row = gate * OO + oo;           // standard w_ih row index

    float wih[OO];
    #pragma unroll
    for (int o = 0; o < OO; o += 4) {
        float4 v = *(const float4*)(w_ih + (size_t)row * OO + o);
        wih[o] = v.x; wih[o + 1] = v.y; wih[o + 2] = v.z; wih[o + 3] = v.w;
    }
    float bj = b_ih[row] + b_hh[row];         // fold conv_b through w_ih
    #pragma unroll
    for (int o = 0; o < OO; o += 4) {
        float4 cb = *(const float4*)(conv_b + o);
        bj = fmaf(cb.x, wih[o], bj);
        bj = fmaf(cb.y, wih[o + 1], bj);
        bj = fmaf(cb.z, wih[o + 2], bj);
        bj = fmaf(cb.w, wih[o + 3], bj);
    }

    __shared__ float feat_sh[2][4][OO];
    int buf = 0;
    const int r0 = blockIdx.x * 16;
    #pragma unroll
    for (int ch = 0; ch < 4; ++ch) {
        const int r = r0 + ch * 4 + wv;       // r = t*NA + n
        const int t = r >> 11;
        const int n = r & (NA - 1);
        const float* Pt = P + ((size_t)t << 17);  // t*NA*OO

        int vA = A[((size_t)r << 5) + (lane & 31)];
        float pm = -INFINITY;
        #pragma unroll
        for (int k = 0; k < KK; ++k) {
            int idx = __builtin_amdgcn_readlane(vA, k);   // SGPR-uniform
            pm = fmaxf(pm, Pt[((size_t)idx << 6) + lane]);
        }
        feat_sh[buf][wv][lane] = pm - Pt[((size_t)n << 6) + lane];
        __syncthreads();

        #pragma unroll
        for (int w2 = 0; w2 < 4; ++w2) {
            float acc = bj;
            #pragma unroll
            for (int o = 0; o < OO; o += 4) {
                float4 f4 = *(const float4*)&feat_sh[buf][w2][o];
                acc = fmaf(f4.x, wih[o], acc);
                acc = fmaf(f4.y, wih[o + 1], acc);
                acc = fmaf(f4.z, wih[o + 2], acc);
                acc = fmaf(f4.w, wih[o + 3], acc);
            }
            gx[((size_t)(r0 + ch * 4 + w2) << 8) + tid] = __float2bfloat16(acc);
        }
        buf ^= 1;   // next chunk writes the other buffer: 1 barrier/chunk
    }
}

// Serial recurrence only: g = gx + h @ w_hh^T, pointwise LSTM cell.
// 2 agents per block (1024 blocks -> 4 blocks/CU resident).  h is kept
// per-wave-private in LDS (every wave redundantly computes the pointwise
// update), so only gsh needs a barrier; gsh double-buffered -> 1 barrier/t.
__global__ __launch_bounds__(256) void lstm_kernel(
    const __hip_bfloat16* __restrict__ gx, const float* __restrict__ w_hh,
    float* __restrict__ out)
{
    const int tid = threadIdx.x;
    const int lane = tid & 63;
    const int wv = tid >> 6;
    const int gate = tid & 3;
    const int oo = tid >> 2;
    const int row = gate * OO + oo;
    const int a0 = blockIdx.x * 2;

    float whh[OO];
    #pragma unroll
    for (int o = 0; o < OO; o += 4) {
        float4 v = *(const float4*)(w_hh + (size_t)row * OO + o);
        whh[o] = v.x; whh[o + 1] = v.y; whh[o + 2] = v.z; whh[o + 3] = v.w;
    }

    __shared__ float gsh[2][2][GG];
    __shared__ float hsh[4][2][OO];
    hsh[wv][0][lane] = 0.f;
    hsh[wv][1][lane] = 0.f;
    float c0 = 0.f, c1 = 0.f;
    // gx already contains the full bias (b_ih + b_hh + conv_b fold)
    float g0 = __bfloat162float(gx[((size_t)a0 << 8) + tid]);
    float g1 = __bfloat162float(gx[((size_t)(a0 + 1) << 8) + tid]);
    int buf = 0;

    for (int t = 0; t < TT; ++t) {
        float acc0 = g0, acc1 = g1;
        #pragma unroll
        for (int o = 0; o < OO; o += 4) {
            float4 h0 = *(const float4*)&hsh[wv][0][o];   // own-wave slot
            float4 h1 = *(const float4*)&hsh[wv][1][o];
            acc0 = fmaf(h0.x, whh[o], acc0);
            acc0 = fmaf(h0.y, whh[o + 1], acc0);
            acc0 = fmaf(h0.z, whh[o + 2], acc0);
            acc0 = fmaf(h0.w, whh[o + 3], acc0);
            acc1 = fmaf(h1.x, whh[o], acc1);
            acc1 = fmaf(h1.y, whh[o + 1], acc1);
            acc1 = fmaf(h1.z, whh[o + 2], acc1);
            acc1 = fmaf(h1.w, whh[o + 3], acc1);
        }
        gsh[buf][0][tid] = acc0;
        gsh[buf][1][tid] = acc1;
        __syncthreads();

        // prefetch next timestep's gx while gsh settles into registers
        int tn = (t + 1 < TT) ? t + 1 : t;
        g0 = __bfloat162float(gx[(((size_t)tn << 11) + a0) * GG + tid]);
        g1 = __bfloat162float(gx[(((size_t)tn << 11) + a0 + 1) * GG + tid]);

        // pointwise cell update, redundant per wave; layout j' = o*4+gate
        float4 q0 = *(const float4*)&gsh[buf][0][lane << 2];
        float4 q1 = *(const float4*)&gsh[buf][1][lane << 2];
        float i0 = sigm(q0.x), f0 = sigm(q0.y);
        float z0 = tanh_fast(q0.z), o0 = sigm(q0.w);
        c0 = fmaf(f0, c0, i0 * z0);
        float h0v = o0 * tanh_fast(c0);
        float i1 = sigm(q1.x), f1 = sigm(q1.y);
        float z1 = tanh_fast(q1.z), o1 = sigm(q1.w);
        c1 = fmaf(f1, c1, i1 * z1);
        float h1v = o1 * tanh_fast(c1);
        hsh[wv][0][lane] = h0v;   // own-wave write; in-order DS, no barrier
        hsh[wv][1][lane] = h1v;

        if (wv == 0) {
            out[((size_t)a0 * TT + t) * OO + lane] = h0v;
            out[((size_t)(a0 + 1) * TT + t) * OO + lane] = h1v;
            if (t == TT - 1) {
                size_t hb = (size_t)NA * TT * OO;
                out[hb + (size_t)a0 * OO + lane] = h0v;
                out[hb + (size_t)(a0 + 1) * OO + lane] = h1v;
                out[hb + (size_t)NA * OO + (size_t)a0 * OO + lane] = c0;
                out[hb + (size_t)NA * OO + (size_t)(a0 + 1) * OO + lane] = c1;
            }
        }
        buf ^= 1;
    }
}

extern "C" void kernel_launch(void* const* d_in, const int* in_sizes, int n_in,
                              void* d_out, int out_size, void* d_ws, size_t ws_size,
                              hipStream_t stream) {
    const float* x      = (const float*)d_in[0];
    const int*   A      = (const int*)  d_in[1];
    const float* conv_w = (const float*)d_in[2];
    const float* conv_b = (const float*)d_in[3];
    const float* w_ih   = (const float*)d_in[4];
    const float* w_hh   = (const float*)d_in[5];
    const float* b_ih   = (const float*)d_in[6];
    const float* b_hh   = (const float*)d_in[7];
    float* out = (float*)d_out;

    float* P = (float*)d_ws;                              // 10.5 MB
    __hip_bfloat16* gx =
        (__hip_bfloat16*)((char*)d_ws + (size_t)TT * NA * OO * sizeof(float));  // 21 MB

    hipLaunchKernelGGL(proj_kernel, dim3(NA * TT / 16), dim3(256), 0, stream,
                       x, conv_w, P);
    hipLaunchKernelGGL(gatemm_kernel, dim3(NA * TT / 16), dim3(256), 0, stream,
                       P, A, conv_b, w_ih, b_ih, b_hh, gx);
    hipLaunchKernelGGL(lstm_kernel, dim3(NA / 2), dim3(256), 0, stream,
                       gx, w_hh, out);
}